// Round 1
// baseline (110.738 us; speedup 1.0000x reference)
//
#include <hip/hip_runtime.h>

#define NJ 22
#define CAM_DIM 3
#define RSTRIDE 224   // per-i: 198 floats R + 22 floats n2 + pad (16B aligned)

// Kernel 1: per-prediction rot6d -> R (22x3x3), per-joint ||R||^2, packed gate key.
__global__ void precompute_kernel(const float* __restrict__ params,
                                  const int* __restrict__ batch_ids,
                                  const int* __restrict__ czyx,
                                  float* __restrict__ ws_R,
                                  int* __restrict__ ws_key,
                                  int n, int param_dim) {
    int i = blockIdx.x * blockDim.x + threadIdx.x;
    if (i >= n) return;

    // packed gate key: batch (0..31) << 16 | y << 8 | x   (y,x in 0..63)
    int b  = batch_ids[i];
    int cy = czyx[i * 3 + 1];
    int cx = czyx[i * 3 + 2];
    ws_key[i] = (b << 16) | (cy << 8) | cx;

    const float* p = params + (size_t)i * param_dim + CAM_DIM;
    float* Ri = ws_R + (size_t)i * RSTRIDE;

    for (int k = 0; k < NJ; ++k) {
        // x[k][r][c]: a1[r] = p[k*6+2r], a2[r] = p[k*6+2r+1]
        float a1x = p[k*6+0], a2x = p[k*6+1];
        float a1y = p[k*6+2], a2y = p[k*6+3];
        float a1z = p[k*6+4], a2z = p[k*6+5];

        float n1 = sqrtf(a1x*a1x + a1y*a1y + a1z*a1z);
        float b1x = a1x / n1, b1y = a1y / n1, b1z = a1z / n1;

        float d = b1x*a2x + b1y*a2y + b1z*a2z;
        float px = a2x - d*b1x, py = a2y - d*b1y, pz = a2z - d*b1z;
        float np = sqrtf(px*px + py*py + pz*pz);
        float b2x = px / np, b2y = py / np, b2z = pz / np;

        float b3x = b1y*b2z - b1z*b2y;
        float b3y = b1z*b2x - b1x*b2z;
        float b3z = b1x*b2y - b1y*b2x;

        float r[9] = {b1x,b1y,b1z,b2x,b2y,b2z,b3x,b3y,b3z};
        float s = 0.0f;
        #pragma unroll
        for (int a = 0; a < 9; ++a) {
            Ri[k*9 + a] = r[a];
            s += r[a] * r[a];
        }
        Ri[198 + k] = s;   // n2[k] — same accumulation order as the dot below
                           // so the diagonal gives exactly 0.
    }
}

// Kernel 2: one block per row i. Gate is cheap (one packed int per j);
// pose distance only where the gate passes (~2 of 2048 j's per row).
__global__ __launch_bounds__(256) void score_kernel(
        const float* __restrict__ ts,
        const float* __restrict__ ws_R,
        const int* __restrict__ ws_key,
        float* __restrict__ out,      // [n, n] score_map
        float* __restrict__ nms,      // [n]
        int n) {
    __shared__ float Ri_sh[220];      // 198 R + 22 n2
    __shared__ float s_best[256];
    __shared__ int   s_bj[256];

    const int i   = blockIdx.x;
    const int tid = threadIdx.x;

    const float* Ri = ws_R + (size_t)i * RSTRIDE;
    if (tid < 220) Ri_sh[tid] = Ri[tid];
    __syncthreads();

    const int key_i = ws_key[i];
    const int bi  = key_i >> 16;
    const int ciy = (key_i >> 8) & 0xff;
    const int cix = key_i & 0xff;

    float best  = -1.0f;
    int   bestj = 0x7fffffff;
    float* row = out + (size_t)i * n;

    const int iters = (n + 255) / 256;   // 8 for n=2048
    for (int t = 0; t < iters; ++t) {
        int j = t * 256 + tid;
        if (j >= n) break;

        int key_j = ws_key[j];
        int dy = ((key_j >> 8) & 0xff) - ciy;
        int dx = (key_j & 0xff) - cix;
        bool ok = ((key_j >> 16) == bi) && (dy*dy + dx*dx <= 25);

        float score = 0.0f;
        if (ok) {
            const float* Rj = ws_R + (size_t)j * RSTRIDE;
            float sum = 0.0f;
            #pragma unroll
            for (int k = 0; k < NJ; ++k) {
                float g = 0.0f;
                #pragma unroll
                for (int a = 0; a < 9; ++a)
                    g += Ri_sh[k*9 + a] * Rj[k*9 + a];
                float d2 = Ri_sh[198 + k] + Rj[198 + k] - 2.0f * g;
                d2 = fmaxf(d2, 0.0f);
                sum += sqrtf(d2);
            }
            float pd = sum / 22.0f;
            if (pd < 2.5f) score = ts[j];
        }
        row[j] = score;
        // first-occurrence argmax: strictly greater, or equal with smaller j
        if (score > best || (score == best && j < bestj)) {
            best = score;
            bestj = j;
        }
    }

    s_best[tid] = best;
    s_bj[tid]   = bestj;
    __syncthreads();
    for (int off = 128; off > 0; off >>= 1) {
        if (tid < off) {
            float ob = s_best[tid + off];
            int   oj = s_bj[tid + off];
            if (ob > s_best[tid] || (ob == s_best[tid] && oj < s_bj[tid])) {
                s_best[tid] = ob;
                s_bj[tid]   = oj;
            }
        }
        __syncthreads();
    }
    if (tid == 0) nms[i] = (s_bj[0] == i) ? 1.0f : 0.0f;
}

extern "C" void kernel_launch(void* const* d_in, const int* in_sizes, int n_in,
                              void* d_out, int out_size, void* d_ws, size_t ws_size,
                              hipStream_t stream) {
    const float* params = (const float*)d_in[0];
    const int*   batch  = (const int*)d_in[1];
    const int*   czyx   = (const int*)d_in[2];
    const float* ts     = (const float*)d_in[3];

    const int n = in_sizes[1];                 // N = 2048
    const int param_dim = in_sizes[0] / n;     // 145

    float* ws_R   = (float*)d_ws;                       // n * RSTRIDE floats
    int*   ws_key = (int*)(ws_R + (size_t)n * RSTRIDE); // n ints

    float* out = (float*)d_out;        // score_map [n*n]
    float* nms = out + (size_t)n * n;  // nms_inds [n] as 0/1 floats

    precompute_kernel<<<(n + 255) / 256, 256, 0, stream>>>(
        params, batch, czyx, ws_R, ws_key, n, param_dim);
    score_kernel<<<n, 256, 0, stream>>>(ts, ws_R, ws_key, out, nms, n);
}

// Round 2
// 35.078 us; speedup vs baseline: 3.1569x; 3.1569x over previous
//
#include <hip/hip_runtime.h>

#define NJ 22
#define CAM_DIM 3
#define RSTRIDE 224   // per-i: 198 floats R + 22 floats n2 + 4 pad

// Kernel 1: one thread per (prediction, joint). Also packs gate key and
// inits the per-row argmax slot (k==0 threads).
__global__ void precompute_kernel(const float* __restrict__ params,
                                  const int* __restrict__ batch_ids,
                                  const int* __restrict__ czyx,
                                  float* __restrict__ ws_R,
                                  int* __restrict__ ws_key,
                                  unsigned long long* __restrict__ slots,
                                  int n, int param_dim) {
    int t = blockIdx.x * blockDim.x + threadIdx.x;
    if (t >= n * NJ) return;
    int i = t / NJ;
    int k = t - i * NJ;

    if (k == 0) {
        int b  = batch_ids[i];
        int cy = czyx[i * 3 + 1];
        int cx = czyx[i * 3 + 2];
        ws_key[i] = (b << 16) | (cy << 8) | cx;
        // init argmax slot: (score=0.0f bits, ~j with j=0)
        slots[i] = 0x00000000FFFFFFFFull;
    }

    const float* p = params + (size_t)i * param_dim + CAM_DIM + k * 6;
    float a1x = p[0], a2x = p[1];
    float a1y = p[2], a2y = p[3];
    float a1z = p[4], a2z = p[5];

    float n1 = sqrtf(a1x*a1x + a1y*a1y + a1z*a1z);
    float b1x = a1x / n1, b1y = a1y / n1, b1z = a1z / n1;

    float d = b1x*a2x + b1y*a2y + b1z*a2z;
    float px = a2x - d*b1x, py = a2y - d*b1y, pz = a2z - d*b1z;
    float np = sqrtf(px*px + py*py + pz*pz);
    float b2x = px / np, b2y = py / np, b2z = pz / np;

    float b3x = b1y*b2z - b1z*b2y;
    float b3y = b1z*b2x - b1x*b2z;
    float b3z = b1x*b2y - b1y*b2x;

    float r[9] = {b1x,b1y,b1z,b2x,b2y,b2z,b3x,b3y,b3z};
    float* Ri = ws_R + (size_t)i * RSTRIDE;
    float s = 0.0f;
    #pragma unroll
    for (int a = 0; a < 9; ++a) {
        Ri[k*9 + a] = r[a];
        s += r[a] * r[a];
    }
    Ri[198 + k] = s;   // same accumulation order as the gate dot -> exact 0 diagonal
}

// Kernel 2: pure streaming zero-fill of the score map (float4 stores).
__global__ void zero_fill_kernel(float* __restrict__ out, long long total) {
    long long idx = (long long)blockIdx.x * blockDim.x + threadIdx.x;
    long long v4 = idx * 4;
    if (v4 + 3 < total) {
        *reinterpret_cast<float4*>(out + v4) = make_float4(0.f, 0.f, 0.f, 0.f);
    } else {
        for (long long r = v4; r < total; ++r) out[r] = 0.0f;
    }
}

// Kernel 3: gate + sparse pose/score. No LDS, no barriers, no dense stores.
// blockIdx.y = row i; each thread handles 4 consecutive j's.
__global__ __launch_bounds__(256) void gate_kernel(
        const float* __restrict__ ts,
        const float* __restrict__ ws_R,
        const int* __restrict__ ws_key,
        float* __restrict__ out,
        unsigned long long* __restrict__ slots,
        int n) {
    const int i  = blockIdx.y;
    const int j0 = blockIdx.x * (blockDim.x * 4) + threadIdx.x * 4;
    if (j0 >= n) return;

    const int key_i = ws_key[i];
    const int bi  = key_i >> 16;
    const int ciy = (key_i >> 8) & 0xff;
    const int cix = key_i & 0xff;

    int kj[4];
    if (j0 + 3 < n) {
        int4 v = *reinterpret_cast<const int4*>(ws_key + j0);
        kj[0] = v.x; kj[1] = v.y; kj[2] = v.z; kj[3] = v.w;
    } else {
        for (int u = 0; u < 4; ++u) kj[u] = (j0 + u < n) ? ws_key[j0 + u] : ~key_i;
    }

    const float* Ri = ws_R + (size_t)i * RSTRIDE;

    #pragma unroll
    for (int u = 0; u < 4; ++u) {
        int j = j0 + u;
        if (j >= n) break;
        int key_j = kj[u];
        int dy = ((key_j >> 8) & 0xff) - ciy;
        int dx = (key_j & 0xff) - cix;
        bool ok = ((key_j >> 16) == bi) && (dy*dy + dx*dx <= 25);
        if (ok) {
            const float* Rj = ws_R + (size_t)j * RSTRIDE;
            float sum = 0.0f;
            #pragma unroll
            for (int k = 0; k < NJ; ++k) {
                float g = 0.0f;
                #pragma unroll
                for (int a = 0; a < 9; ++a)
                    g += Ri[k*9 + a] * Rj[k*9 + a];
                float d2 = Ri[198 + k] + Rj[198 + k] - 2.0f * g;
                d2 = fmaxf(d2, 0.0f);
                sum += sqrtf(d2);
            }
            float pd = sum / 22.0f;
            if (pd < 2.5f) {
                float s = ts[j];
                out[(size_t)i * n + j] = s;
                unsigned long long packed =
                    ((unsigned long long)__float_as_uint(s) << 32) |
                    (unsigned int)(~(unsigned int)j);
                atomicMax(slots + i, packed);
            }
        }
    }
}

// Kernel 4: unpack argmax winner -> nms 0/1.
__global__ void nms_kernel(const unsigned long long* __restrict__ slots,
                           float* __restrict__ nms, int n) {
    int i = blockIdx.x * blockDim.x + threadIdx.x;
    if (i >= n) return;
    unsigned int jwin = ~(unsigned int)(slots[i] & 0xFFFFFFFFull);
    nms[i] = (jwin == (unsigned int)i) ? 1.0f : 0.0f;
}

extern "C" void kernel_launch(void* const* d_in, const int* in_sizes, int n_in,
                              void* d_out, int out_size, void* d_ws, size_t ws_size,
                              hipStream_t stream) {
    const float* params = (const float*)d_in[0];
    const int*   batch  = (const int*)d_in[1];
    const int*   czyx   = (const int*)d_in[2];
    const float* ts     = (const float*)d_in[3];

    const int n = in_sizes[1];                 // N = 2048
    const int param_dim = in_sizes[0] / n;     // 145

    float* ws_R   = (float*)d_ws;                               // n*RSTRIDE f32
    int*   ws_key = (int*)(ws_R + (size_t)n * RSTRIDE);         // n i32
    unsigned long long* slots =
        (unsigned long long*)(ws_key + n);                      // n u64 (8B-aligned)

    float* out = (float*)d_out;        // score_map [n*n]
    float* nms = out + (size_t)n * n;  // nms_inds [n] as 0/1 floats

    precompute_kernel<<<(n * NJ + 255) / 256, 256, 0, stream>>>(
        params, batch, czyx, ws_R, ws_key, slots, n, param_dim);

    long long total = (long long)n * n;
    int zb = (int)((total / 4 + 255) / 256) + 1;
    zero_fill_kernel<<<zb, 256, 0, stream>>>(out, total);

    dim3 ggrid((n + 1023) / 1024, n);
    gate_kernel<<<ggrid, 256, 0, stream>>>(ts, ws_R, ws_key, out, slots, n);

    nms_kernel<<<(n + 255) / 256, 256, 0, stream>>>(slots, nms, n);
}

// Round 3
// 34.280 us; speedup vs baseline: 3.2304x; 1.0233x over previous
//
#include <hip/hip_runtime.h>

#define NJ 22
#define CAM_DIM 3
#define RSTRIDE 224   // per-i: 198 floats R + 22 floats n2 + 4 pad

// Kernel 1: one thread per (prediction, joint). Also packs gate key and
// inits the per-row argmax slot (k==0 threads).
__global__ void precompute_kernel(const float* __restrict__ params,
                                  const int* __restrict__ batch_ids,
                                  const int* __restrict__ czyx,
                                  float* __restrict__ ws_R,
                                  int* __restrict__ ws_key,
                                  unsigned long long* __restrict__ slots,
                                  int n, int param_dim) {
    int t = blockIdx.x * blockDim.x + threadIdx.x;
    if (t >= n * NJ) return;
    int i = t / NJ;
    int k = t - i * NJ;

    if (k == 0) {
        int b  = batch_ids[i];
        int cy = czyx[i * 3 + 1];
        int cx = czyx[i * 3 + 2];
        ws_key[i] = (b << 16) | (cy << 8) | cx;
        slots[i] = 0x00000000FFFFFFFFull;   // (score=0.0 bits, ~j with j=0)
    }

    const float* p = params + (size_t)i * param_dim + CAM_DIM + k * 6;
    float a1x = p[0], a2x = p[1];
    float a1y = p[2], a2y = p[3];
    float a1z = p[4], a2z = p[5];

    float n1 = sqrtf(a1x*a1x + a1y*a1y + a1z*a1z);
    float b1x = a1x / n1, b1y = a1y / n1, b1z = a1z / n1;

    float d = b1x*a2x + b1y*a2y + b1z*a2z;
    float px = a2x - d*b1x, py = a2y - d*b1y, pz = a2z - d*b1z;
    float np = sqrtf(px*px + py*py + pz*pz);
    float b2x = px / np, b2y = py / np, b2z = pz / np;

    float b3x = b1y*b2z - b1z*b2y;
    float b3y = b1z*b2x - b1x*b2z;
    float b3z = b1x*b2y - b1y*b2x;

    float r[9] = {b1x,b1y,b1z,b2x,b2y,b2z,b3x,b3y,b3z};
    float* Ri = ws_R + (size_t)i * RSTRIDE;
    float s = 0.0f;
    #pragma unroll
    for (int a = 0; a < 9; ++a) {
        Ri[k*9 + a] = r[a];
        s += r[a] * r[a];
    }
    Ri[198 + k] = s;   // same accumulation order as the pair dot -> exact 0 diagonal
}

// Kernel 2 (fused): one block per row. Each thread produces 8 consecutive j's
// and stores them densely as two float4s (zero unless the sparse gate passes).
// Single pass over the 16.8 MB map — pure streaming write.
__global__ __launch_bounds__(256) void fused_score_kernel(
        const float* __restrict__ ts,
        const float* __restrict__ ws_R,
        const int* __restrict__ ws_key,
        float* __restrict__ out,
        unsigned long long* __restrict__ slots,
        int n) {
    const int i   = blockIdx.x;
    const int tid = threadIdx.x;

    const int key_i = ws_key[i];
    const int bi  = key_i >> 16;
    const int ciy = (key_i >> 8) & 0xff;
    const int cix = key_i & 0xff;
    const float* Ri = ws_R + (size_t)i * RSTRIDE;
    float* row = out + (size_t)i * n;

    for (int j0 = tid * 8; j0 < n; j0 += blockDim.x * 8) {
        int kj[8];
        if (j0 + 7 < n) {
            int4 ka = *reinterpret_cast<const int4*>(ws_key + j0);
            int4 kb = *reinterpret_cast<const int4*>(ws_key + j0 + 4);
            kj[0]=ka.x; kj[1]=ka.y; kj[2]=ka.z; kj[3]=ka.w;
            kj[4]=kb.x; kj[5]=kb.y; kj[6]=kb.z; kj[7]=kb.w;
        } else {
            for (int u = 0; u < 8; ++u)
                kj[u] = (j0 + u < n) ? ws_key[j0 + u] : ~key_i;
        }

        float sc[8];
        #pragma unroll
        for (int u = 0; u < 8; ++u) {
            int key_j = kj[u];
            int dy = ((key_j >> 8) & 0xff) - ciy;
            int dx = (key_j & 0xff) - cix;
            bool ok = ((key_j >> 16) == bi) && (dy*dy + dx*dx <= 25);
            float s = 0.0f;
            if (ok) {
                int j = j0 + u;
                const float* Rj = ws_R + (size_t)j * RSTRIDE;
                float sum = 0.0f;
                #pragma unroll
                for (int k = 0; k < NJ; ++k) {
                    float g = 0.0f;
                    #pragma unroll
                    for (int a = 0; a < 9; ++a)
                        g += Ri[k*9 + a] * Rj[k*9 + a];
                    float d2 = Ri[198 + k] + Rj[198 + k] - 2.0f * g;
                    d2 = fmaxf(d2, 0.0f);
                    sum += sqrtf(d2);
                }
                float pd = sum / 22.0f;
                if (pd < 2.5f) {
                    s = ts[j];
                    unsigned long long packed =
                        ((unsigned long long)__float_as_uint(s) << 32) |
                        (unsigned int)(~(unsigned int)j);
                    atomicMax(slots + i, packed);
                }
            }
            sc[u] = s;
        }

        if (j0 + 7 < n) {
            *reinterpret_cast<float4*>(row + j0)     = make_float4(sc[0],sc[1],sc[2],sc[3]);
            *reinterpret_cast<float4*>(row + j0 + 4) = make_float4(sc[4],sc[5],sc[6],sc[7]);
        } else {
            for (int u = 0; u < 8 && j0 + u < n; ++u) row[j0 + u] = sc[u];
        }
    }
}

// Kernel 3: unpack argmax winner -> nms 0/1.
__global__ void nms_kernel(const unsigned long long* __restrict__ slots,
                           float* __restrict__ nms, int n) {
    int i = blockIdx.x * blockDim.x + threadIdx.x;
    if (i >= n) return;
    unsigned int jwin = ~(unsigned int)(slots[i] & 0xFFFFFFFFull);
    nms[i] = (jwin == (unsigned int)i) ? 1.0f : 0.0f;
}

extern "C" void kernel_launch(void* const* d_in, const int* in_sizes, int n_in,
                              void* d_out, int out_size, void* d_ws, size_t ws_size,
                              hipStream_t stream) {
    const float* params = (const float*)d_in[0];
    const int*   batch  = (const int*)d_in[1];
    const int*   czyx   = (const int*)d_in[2];
    const float* ts     = (const float*)d_in[3];

    const int n = in_sizes[1];                 // N = 2048
    const int param_dim = in_sizes[0] / n;     // 145

    float* ws_R   = (float*)d_ws;                               // n*RSTRIDE f32
    int*   ws_key = (int*)(ws_R + (size_t)n * RSTRIDE);         // n i32
    unsigned long long* slots =
        (unsigned long long*)(ws_key + n);                      // n u64 (8B-aligned)

    float* out = (float*)d_out;        // score_map [n*n]
    float* nms = out + (size_t)n * n;  // nms_inds [n] as 0/1 floats

    precompute_kernel<<<(n * NJ + 255) / 256, 256, 0, stream>>>(
        params, batch, czyx, ws_R, ws_key, slots, n, param_dim);

    fused_score_kernel<<<n, 256, 0, stream>>>(ts, ws_R, ws_key, out, slots, n);

    nms_kernel<<<(n + 255) / 256, 256, 0, stream>>>(slots, nms, n);
}